// Round 8
// baseline (140.715 us; speedup 1.0000x reference)
//
#include <hip/hip_runtime.h>
#include <stdint.h>

#define CC 6
#define BB 4096
#define TT 512
#define HH 26
#define NSEQ (CC*BB)      // 24576
#define FF (CC*HH)        // 156
#define NBIN (CC*TT)      // 3072

typedef _Float16 f16x8 __attribute__((ext_vector_type(8)));
typedef _Float16 f16x2 __attribute__((ext_vector_type(2)));
typedef float    f32x4 __attribute__((ext_vector_type(4)));
typedef int      i32x4 __attribute__((ext_vector_type(4)));

__device__ __forceinline__ float fexp2(float x){ return __builtin_amdgcn_exp2f(x); }
__device__ __forceinline__ float frcp(float x){ return __builtin_amdgcn_rcpf(x); }
__device__ __forceinline__ int pkf16(float a, float b){
  return __builtin_bit_cast(int, __builtin_amdgcn_cvt_pkrtz(a, b));
}

// ---------------- fused counting sort (single block): key = c*512 + (512-len) ----------------
// Proven in round 2. Each channel owns 4096 slots of perm, longest-first within channel.

__global__ __launch_bounds__(1024) void sort_kernel(const int* __restrict__ lengths,
                                                    unsigned int* __restrict__ perm) {
  __shared__ unsigned int hist[NBIN];
  __shared__ unsigned int curs[NBIN];
  __shared__ unsigned int tmp[1024];
  const int t = threadIdx.x;
  for (int i = t; i < NBIN; i += 1024) hist[i] = 0u;
  __syncthreads();
#pragma unroll
  for (int i = 0; i < 24; ++i) {
    int s = t + i * 1024;
    int c = s >> 12, b = s & 4095;
    int len = lengths[b * CC + c];               // 1..512
    atomicAdd(&hist[(c << 9) | (TT - len)], 1u);
  }
  __syncthreads();
  unsigned a0 = hist[3*t], a1 = hist[3*t+1], a2 = hist[3*t+2];
  unsigned ts = a0 + a1 + a2;
  tmp[t] = ts;
  __syncthreads();
  for (int d = 1; d < 1024; d <<= 1) {
    unsigned int v = (t >= d) ? tmp[t - d] : 0u;
    __syncthreads();
    tmp[t] += v;
    __syncthreads();
  }
  unsigned excl = tmp[t] - ts;
  hist[3*t]   = excl;
  hist[3*t+1] = excl + a0;
  hist[3*t+2] = excl + a0 + a1;
  curs[3*t] = 0u; curs[3*t+1] = 0u; curs[3*t+2] = 0u;
  __syncthreads();
#pragma unroll
  for (int i = 0; i < 24; ++i) {
    int s = t + i * 1024;
    int c = s >> 12, b = s & 4095;
    int len = lengths[b * CC + c];
    int bin = (c << 9) | (TT - len);
    unsigned p = atomicAdd(&curs[bin], 1u);
    perm[hist[bin] + p] = (unsigned)s;
  }
}

// ---------------- RNN: one wave = 16 same-channel sequences, zero-crossbar MFMA ----------------
// Fixed-point layout (proven r5-7): A row-slot m holds W' row m; A col-slot kappa = 8g+j samples
// W' column sigma(kappa) = 4g+j (j<4) | 16+4g+(j-4) (j>=4). D at lane (g,n) — rows {4g..4g+3}
// (D1) and {16+4g..+3} (D2) — IS the next step's B fragment. x cols (sigma=26,27) = grp2's b3;
// zero cols (28..31) = grp3's b2,b3 — and since A2/Cb2 rows >=26 are zero, D2's fake rows are 0
// and tanh(0)=0 keeps them zero with NO masking.
// tanh: phase-separated, paired-rcp: 8 exp2 -> 8 add -> 4 mul -> 4 rcp -> 8 mul -> 8 fma -> 4 pack.

__device__ __forceinline__ void rnn_chain(
    int c, int rank,
    const float* __restrict__ x, const int* __restrict__ lengths,
    const float* __restrict__ Wih, const float* __restrict__ Whh,
    const float* __restrict__ bih, const float* __restrict__ bhh,
    const unsigned* __restrict__ perm, float* __restrict__ fbuf)
{
  const int l = threadIdx.x & 63, col = l & 15, grp = l >> 4;
  const int chain0 = c * 256 + rank;

  const unsigned sid = perm[chain0 * 16 + col];
  const int bi = (int)(sid & 4095u);
  const int len = lengths[bi * CC + c];

  int ml = len;
#pragma unroll
  for (int m = 8; m >= 1; m >>= 1) { int o = __shfl_xor(ml, m); ml = ml > o ? ml : o; }

  const float S = 2.0f * 1.44269504088896340736f;
  const float* WhhC = Whh + (size_t)c * HH * HH;
  const float* WihC = Wih + (size_t)c * HH * 2;

  f16x8 A1, A2;
#pragma unroll
  for (int j = 0; j < 8; ++j) {
    const int kk = (j < 4) ? (grp * 4 + j) : (12 + grp * 4 + j);  // sigma(8*grp+j)
    float v1 = (kk < HH) ? WhhC[col * HH + kk] : ((kk < HH + 2) ? WihC[col * 2 + (kk - HH)] : 0.f);
    A1[j] = (_Float16)(S * v1);
    const int m2 = 16 + col;
    float v2 = 0.f;
    if (m2 < HH) v2 = (kk < HH) ? WhhC[m2 * HH + kk] : ((kk < HH + 2) ? WihC[m2 * 2 + (kk - HH)] : 0.f);
    A2[j] = (_Float16)(S * v2);
  }
  f32x4 Cb1, Cb2;
#pragma unroll
  for (int i = 0; i < 4; ++i) {
    int m1 = grp * 4 + i;
    Cb1[i] = S * (bih[c * HH + m1] + bhh[c * HH + m1]);
    int m2 = 16 + grp * 4 + i;
    Cb2[i] = (m2 < HH) ? S * (bih[c * HH + m2] + bhh[c * HH + m2]) : 0.f;
  }

  int b0 = 0, b1 = 0, b2 = 0, b3 = 0;
  const bool isg2 = (grp == 2);
  const float* xp = x + (size_t)sid * (TT * 2);

  // 8-step chunks, double-buffered: 4 x float4 = 16 floats = steps [TT-8-8*cc .. TT-1-8*cc]
  float4 X0 = make_float4(0,0,0,0), X1 = X0, X2 = X0, X3 = X0;
  if (isg2) {
    const float* p0 = xp + (TT - 8) * 2;
    X0 = *(const float4*)(p0 + 0);
    X1 = *(const float4*)(p0 + 4);
    X2 = *(const float4*)(p0 + 8);
    X3 = *(const float4*)(p0 + 12);
  }

  const int nch = (ml + 7) >> 3;
  for (int cc = 0; cc < nch; ++cc) {
    float4 N0 = X0, N1 = X1, N2 = X2, N3 = X3;
    if (isg2 && cc < 63) {
      const float* pn = xp + (TT - 16 - 8 * cc) * 2;
      N0 = *(const float4*)(pn + 0);
      N1 = *(const float4*)(pn + 4);
      N2 = *(const float4*)(pn + 8);
      N3 = *(const float4*)(pn + 12);
    }
    const float xq[16] = {X0.x, X0.y, X0.z, X0.w, X1.x, X1.y, X1.z, X1.w,
                          X2.x, X2.y, X2.z, X2.w, X3.x, X3.y, X3.z, X3.w};
#pragma unroll
    for (int j = 0; j < 8; ++j) {
      const int t = 8 * cc + j;
      int px = pkf16(xq[(7 - j) * 2], xq[(7 - j) * 2 + 1]);   // (x0, x1) at step t
      int e3 = isg2 ? px : b3;
      i32x4 bv = {b0, b1, b2, e3};
      f16x8 B = __builtin_bit_cast(f16x8, bv);
      f32x4 D1 = __builtin_amdgcn_mfma_f32_16x16x32_f16(A1, B, Cb1, 0, 0, 0);
      f32x4 D2 = __builtin_amdgcn_mfma_f32_16x16x32_f16(A2, B, Cb2, 0, 0, 0);
      // --- phase-separated tanh, paired rcp ---
      float E0 = fexp2(D1[0]), E1 = fexp2(D1[1]), E2 = fexp2(D1[2]), E3 = fexp2(D1[3]);
      float F0 = fexp2(D2[0]), F1 = fexp2(D2[1]), F2 = fexp2(D2[2]), F3 = fexp2(D2[3]);
      float S0 = E0 + 1.f, S1 = E1 + 1.f, S2 = E2 + 1.f, S3 = E3 + 1.f;
      float T0 = F0 + 1.f, T1 = F1 + 1.f, T2 = F2 + 1.f, T3 = F3 + 1.f;
      float M0 = S0 * S1, M1 = S2 * S3, M2 = T0 * T1, M3 = T2 * T3;
      float R0 = frcp(M0), R1 = frcp(M1), R2 = frcp(M2), R3 = frcp(M3);
      float Y0 = S1 * R0, Y1 = S0 * R0, Y2 = S3 * R1, Y3 = S2 * R1;
      float Z0 = T1 * R2, Z1 = T0 * R2, Z2 = T3 * R3, Z3 = T2 * R3;
      int n0 = pkf16(fmaf(-2.f, Y0, 1.f), fmaf(-2.f, Y1, 1.f));
      int n1 = pkf16(fmaf(-2.f, Y2, 1.f), fmaf(-2.f, Y3, 1.f));
      int n2 = pkf16(fmaf(-2.f, Z0, 1.f), fmaf(-2.f, Z1, 1.f));
      int n3 = pkf16(fmaf(-2.f, Z2, 1.f), fmaf(-2.f, Z3, 1.f));
      const bool upd = t < len;
      b0 = upd ? n0 : b0;
      b1 = upd ? n1 : b1;
      b2 = upd ? n2 : b2;
      b3 = upd ? n3 : b3;
    }
    X0 = N0; X1 = N1; X2 = N2; X3 = N3;
  }

  // epilogue: lane (g,n) holds h[4g..4g+3] in b0,b1 and h[16+4g..16+4g+3] in b2,b3
  const int ma = grp * 4;
  const int mb = 16 + grp * 4;
  float* fb = fbuf + (size_t)bi * FF + c * HH;
  f16x2 p;
  p = __builtin_bit_cast(f16x2, b0);
  fb[25 - (ma + 0)] = fmaxf((float)p[0], 0.f);
  fb[25 - (ma + 1)] = fmaxf((float)p[1], 0.f);
  p = __builtin_bit_cast(f16x2, b1);
  fb[25 - (ma + 2)] = fmaxf((float)p[0], 0.f);
  fb[25 - (ma + 3)] = fmaxf((float)p[1], 0.f);
  p = __builtin_bit_cast(f16x2, b2);
  if (mb + 0 < HH) fb[25 - (mb + 0)] = fmaxf((float)p[0], 0.f);
  if (mb + 1 < HH) fb[25 - (mb + 1)] = fmaxf((float)p[1], 0.f);
  p = __builtin_bit_cast(f16x2, b3);
  if (mb + 2 < HH) fb[25 - (mb + 2)] = fmaxf((float)p[0], 0.f);
  if (mb + 3 < HH) fb[25 - (mb + 3)] = fmaxf((float)p[1], 0.f);
}

// Static queue schedule, placement-proof: 256 blocks x 256 threads -> 1 block/CU, 4 waves on
// the CU's 4 SIMDs -> every wave issue-solo.
// Wave w: w < 512 -> solo chain w (longest). w >= 512 -> chains {w, 2047-w} back-to-back.

__global__ __launch_bounds__(256, 1) void rnn_kernel(
    const float* __restrict__ x, const int* __restrict__ lengths,
    const float* __restrict__ Wih, const float* __restrict__ Whh,
    const float* __restrict__ bih, const float* __restrict__ bhh,
    const unsigned* __restrict__ perm, float* __restrict__ fbuf)
{
  const int w = blockIdx.x * 4 + (threadIdx.x >> 6);   // 0..1023
  if (w < 512) {
    rnn_chain(w % CC, w / CC, x, lengths, Wih, Whh, bih, bhh, perm, fbuf);
  } else {
    const int g1 = w;
    const int g2 = 2047 - w;
    rnn_chain(g1 % CC, g1 / CC, x, lengths, Wih, Whh, bih, bhh, perm, fbuf);
    rnn_chain(g2 % CC, g2 / CC, x, lengths, Wih, Whh, bih, bhh, perm, fbuf);
  }
}

// ---------------- fused 3-layer MLP: 4 rows/block, 1024 blocks ----------------

__global__ __launch_bounds__(256) void mlp_kernel(
    const float* __restrict__ fbuf,
    const float* __restrict__ W1, const float* __restrict__ b1p,
    const float* __restrict__ W2, const float* __restrict__ b2p,
    const float* __restrict__ W3, const float* __restrict__ b3p,
    float* __restrict__ out)
{
  __shared__ float fsh[4 * FF];
  __shared__ float h1sh[4 * 300];
  __shared__ float h2sh[4 * 50];
  const int base = blockIdx.x * 4;
  for (int i = threadIdx.x; i < 4 * FF; i += 256) fsh[i] = fbuf[(size_t)base * FF + i];
  __syncthreads();
  const int rr = threadIdx.x & 3;
  const int ch = threadIdx.x >> 2;               // 0..63
  const float4* frow = (const float4*)&fsh[rr * FF];
  for (int j = ch; j < 300; j += 64) {
    const float4* wrow = (const float4*)&W1[(size_t)j * FF];
    float ax = 0.f, ay = 0.f, az = 0.f, aw = 0.f;
#pragma unroll 13
    for (int k = 0; k < FF / 4; ++k) {
      float4 f = frow[k]; float4 w = wrow[k];
      ax = fmaf(f.x, w.x, ax); ay = fmaf(f.y, w.y, ay);
      az = fmaf(f.z, w.z, az); aw = fmaf(f.w, w.w, aw);
    }
    h1sh[rr * 300 + j] = fmaxf(b1p[j] + (ax + ay) + (az + aw), 0.f);
  }
  __syncthreads();
  const float4* hrow = (const float4*)&h1sh[rr * 300];
  for (int j = ch; j < 50; j += 64) {
    const float4* wrow = (const float4*)&W2[(size_t)j * 300];
    float ax = 0.f, ay = 0.f, az = 0.f, aw = 0.f;
#pragma unroll 15
    for (int k = 0; k < 75; ++k) {
      float4 h = hrow[k]; float4 w = wrow[k];
      ax = fmaf(h.x, w.x, ax); ay = fmaf(h.y, w.y, ay);
      az = fmaf(h.z, w.z, az); aw = fmaf(h.w, w.w, aw);
    }
    h2sh[rr * 50 + j] = fmaxf(b2p[j] + (ax + ay) + (az + aw), 0.f);
  }
  __syncthreads();
  for (int idx = threadIdx.x; idx < 4 * 14; idx += 256) {
    int r2 = idx / 14;
    int j = idx - r2 * 14;
    float a0 = 0.f, a1 = 0.f;
    const float* h2 = &h2sh[r2 * 50];
    const float* wv = &W3[(size_t)j * 50];
#pragma unroll
    for (int k = 0; k < 25; ++k) {
      a0 = fmaf(h2[2*k],   wv[2*k],   a0);
      a1 = fmaf(h2[2*k+1], wv[2*k+1], a1);
    }
    out[(size_t)(base + r2) * 14 + j] = fmaxf(b3p[j] + a0 + a1, 0.f);
  }
}

// ---------------- launch ----------------

extern "C" void kernel_launch(void* const* d_in, const int* in_sizes, int n_in,
                              void* d_out, int out_size, void* d_ws, size_t ws_size,
                              hipStream_t stream) {
  (void)in_sizes; (void)n_in; (void)out_size; (void)ws_size;
  const float* x       = (const float*)d_in[0];
  const int*   lengths = (const int*)  d_in[1];
  const float* Wih     = (const float*)d_in[2];
  const float* Whh     = (const float*)d_in[3];
  const float* bih     = (const float*)d_in[4];
  const float* bhh     = (const float*)d_in[5];
  const float* W1      = (const float*)d_in[6];
  const float* b1      = (const float*)d_in[7];
  const float* W2      = (const float*)d_in[8];
  const float* b2      = (const float*)d_in[9];
  const float* W3      = (const float*)d_in[10];
  const float* b3      = (const float*)d_in[11];
  float* out = (float*)d_out;

  unsigned* perm = (unsigned*)d_ws;
  float* fbuf = (float*)(perm + NSEQ);

  sort_kernel<<<1, 1024, 0, stream>>>(lengths, perm);
  rnn_kernel<<<256, 256, 0, stream>>>(x, lengths, Wih, Whh, bih, bhh, perm, fbuf);
  mlp_kernel<<<BB / 4, 256, 0, stream>>>(fbuf, W1, b1, W2, b2, W3, b3, out);
}